// Round 8
// baseline (36.589 us; speedup 1.0000x reference)
//
#include <hip/hip_runtime.h>
#include <hip/hip_bf16.h>

// InfoNCE-style loss: Xn=normalize(X), Yn=normalize(Y), logits=Xn@Yn^T/0.07,
// loss = mean_i(lse_i - logits[i,i]).
// Fixed-max trick: logits <= 1/T, so lse = 1/T + ln(sum_j exp(logit-1/T)).
// fp8 e4m3 inputs, MX-scaled mfma_scale_f32_16x16x128_f8f6f4, scale=1.0.
// R8: barrier-free logits kernel — each wave stages its OWN 8KB B-tile copy
// (4 waves x 2 bufs x 8KB = 64KB LDS), counted s_waitcnt vmcnt(8) per wave,
// zero s_barrier in the main loop. Waves drift freely -> MFMA overlap.
//
// ws layout:
//   [0,2MB)        Xq fp8 [8192][256]
//   [2MB,4MB)      Yq fp8 [8192][256]
//   [4MB,+32KB)    diag f32[8192]
//   [4MB+32K,+32K) row_sum f32[8192]  (zeroed by nrm_kernel each call)

typedef __attribute__((ext_vector_type(2)))  float f32x2;
typedef __attribute__((ext_vector_type(4)))  float f32x4;
typedef __attribute__((ext_vector_type(4)))  int   i32x4;
typedef __attribute__((ext_vector_type(8)))  int   i32x8;

#define AS1(p) ((const __attribute__((address_space(1))) void*)(uintptr_t)(p))
#define AS3(p) ((__attribute__((address_space(3))) void*)(uintptr_t)(p))

constexpr int   BROWS = 8192;
constexpr int   DDIM  = 256;
constexpr float kInvT = 14.285714285714286f;   // 1/0.07
constexpr float kC1   = 20.609929155556622f;   // log2(e)/0.07
constexpr float kLn2  = 0.6931471805599453f;
constexpr int   kSC   = 0x7F7F7F7F;            // e8m0 scale bytes = 2^0 = 1.0

#if __has_builtin(__builtin_amdgcn_exp2f)
#define EXP2F(x) __builtin_amdgcn_exp2f(x)
#else
#define EXP2F(x) exp2f(x)
#endif
#if __has_builtin(__builtin_amdgcn_logf)
#define LOG2F(x) __builtin_amdgcn_logf(x)
#else
#define LOG2F(x) log2f(x)
#endif

// ---- f32 -> fp8 e4m3fn (RNE). Inputs here are |v| <= 1, finite. ----
static __device__ __forceinline__ unsigned f2fp8(float f) {
  unsigned u = __builtin_bit_cast(unsigned, f);
  unsigned s = (u >> 24) & 0x80u;
  float af = __builtin_fabsf(f);
  if (af < 0.015625f) {                    // below min normal 2^-6: denorm steps 2^-9
    int q = (int)__builtin_rintf(af * 512.0f);   // 0..8 (8 rolls into min normal)
    return s | (unsigned)q;
  }
  unsigned au = u & 0x7FFFFFFFu;
  au += 0x7FFFFu + ((au >> 20) & 1u);      // RNE on 3-bit mantissa
  unsigned e8 = ((au >> 23) - 127u + 7u) & 0xFu;
  unsigned m  = (au >> 20) & 7u;
  return s | (e8 << 3) | m;
}

// ---------------- normalize rows -> fp8, exact fp32 diagonal, zero row_sum --
__global__ __launch_bounds__(256) void nrm_kernel(
    const float* __restrict__ X, const float* __restrict__ Y,
    unsigned int* __restrict__ Xq, unsigned int* __restrict__ Yq,
    float* __restrict__ diag, float* __restrict__ row_sum)
{
  const int wave = threadIdx.x >> 6;
  const int lane = threadIdx.x & 63;
  const int row  = blockIdx.x * 4 + wave;
  const float4 x = *(const float4*)(X + (size_t)row * DDIM + lane * 4);
  const float4 y = *(const float4*)(Y + (size_t)row * DDIM + lane * 4);
  float ssx = x.x*x.x + x.y*x.y + x.z*x.z + x.w*x.w;
  float ssy = y.x*y.x + y.y*y.y + y.z*y.z + y.w*y.w;
  float dot = x.x*y.x + x.y*y.y + x.z*y.z + x.w*y.w;
  #pragma unroll
  for (int m = 1; m < 64; m <<= 1) {
    ssx += __shfl_xor(ssx, m);
    ssy += __shfl_xor(ssy, m);
    dot += __shfl_xor(dot, m);
  }
  const float invx = 1.0f / fmaxf(sqrtf(ssx), 1e-8f);
  const float invy = 1.0f / fmaxf(sqrtf(ssy), 1e-8f);
#if __has_builtin(__builtin_amdgcn_cvt_pk_fp8_f32)
  int xq = __builtin_amdgcn_cvt_pk_fp8_f32(x.x * invx, x.y * invx, 0, false);
  xq     = __builtin_amdgcn_cvt_pk_fp8_f32(x.z * invx, x.w * invx, xq, true);
  int yq = __builtin_amdgcn_cvt_pk_fp8_f32(y.x * invy, y.y * invy, 0, false);
  yq     = __builtin_amdgcn_cvt_pk_fp8_f32(y.z * invy, y.w * invy, yq, true);
#else
  int xq = (int)(f2fp8(x.x*invx) | (f2fp8(x.y*invx) << 8) |
                 (f2fp8(x.z*invx) << 16) | (f2fp8(x.w*invx) << 24));
  int yq = (int)(f2fp8(y.x*invy) | (f2fp8(y.y*invy) << 8) |
                 (f2fp8(y.z*invy) << 16) | (f2fp8(y.w*invy) << 24));
#endif
  Xq[row * 64 + lane] = (unsigned)xq;
  Yq[row * 64 + lane] = (unsigned)yq;
  if (lane == 0) {
    diag[row] = dot * invx * invy * kInvT;
    row_sum[row] = 0.0f;
  }
}

// -------- exp-flush of one m-slice of the PREVIOUS tile's accumulators ------
static __device__ __forceinline__ void expflush(f32x4 (&pm)[2], f32x2 (&sm)[2]) {
  #pragma unroll
  for (int n = 0; n < 2; ++n) {
    f32x2 v0 = { pm[n][0], pm[n][1] };
    f32x2 v1 = { pm[n][2], pm[n][3] };
    v0 = v0 * kC1 + (f32x2){-kC1, -kC1};   // v_pk_fma_f32
    v1 = v1 * kC1 + (f32x2){-kC1, -kC1};
    sm[0] += (f32x2){ EXP2F(v0.x), EXP2F(v0.y) };
    sm[1] += (f32x2){ EXP2F(v1.x), EXP2F(v1.y) };
  }
}

// -------- one B-tile (32 Y-rows x 256B fp8): 16 MX-MFMAs + T15 exp overlap --
// kb=0 MFMAs write cur fresh (C = literal 0 -> no acc zeroing, no WAR with
// prev), kb=1 accumulates. exp of prev[0..1] hides under kb=1's reads/MFMAs.
static __device__ __forceinline__ void tile_step(
    const char* __restrict__ tb, const int (&bb)[2][2], const i32x8 (&a)[4][2],
    f32x4 (&cur)[4][2], f32x4 (&prev)[4][2], f32x2 (&sums2)[4][2])
{
  i32x8 b[2];
  __builtin_amdgcn_s_setprio(1);
  #pragma unroll
  for (int n = 0; n < 2; ++n) {
    const i32x4 lo = *(const i32x4*)(tb + bb[n][0]);
    const i32x4 hi = *(const i32x4*)(tb + bb[n][1]);
    b[n] = __builtin_shufflevector(lo, hi, 0, 1, 2, 3, 4, 5, 6, 7);
  }
  #pragma unroll
  for (int m = 0; m < 4; ++m) {
    cur[m][0] = __builtin_amdgcn_mfma_scale_f32_16x16x128_f8f6f4(
        a[m][0], b[0], (f32x4){0.f, 0.f, 0.f, 0.f}, 0, 0, 0, kSC, 0, kSC);
    cur[m][1] = __builtin_amdgcn_mfma_scale_f32_16x16x128_f8f6f4(
        a[m][0], b[1], (f32x4){0.f, 0.f, 0.f, 0.f}, 0, 0, 0, kSC, 0, kSC);
  }
  __builtin_amdgcn_s_setprio(0);
  expflush(prev[0], sums2[0]);
  expflush(prev[1], sums2[1]);
  __builtin_amdgcn_s_setprio(1);
  #pragma unroll
  for (int n = 0; n < 2; ++n) {
    const i32x4 lo = *(const i32x4*)(tb + bb[n][0] + 128);
    const i32x4 hi = *(const i32x4*)(tb + bb[n][1] + 128);
    b[n] = __builtin_shufflevector(lo, hi, 0, 1, 2, 3, 4, 5, 6, 7);
  }
  #pragma unroll
  for (int m = 0; m < 4; ++m) {
    cur[m][0] = __builtin_amdgcn_mfma_scale_f32_16x16x128_f8f6f4(
        a[m][1], b[0], cur[m][0], 0, 0, 0, kSC, 0, kSC);
    cur[m][1] = __builtin_amdgcn_mfma_scale_f32_16x16x128_f8f6f4(
        a[m][1], b[1], cur[m][1], 0, 0, 0, kSC, 0, kSC);
  }
  __builtin_amdgcn_s_setprio(0);
  expflush(prev[2], sums2[2]);
  expflush(prev[3], sums2[3]);
}

// ---------------- main: exp-sum of logits over all columns ----------------
// 512 blocks x 256 thr (4 waves). Wave owns 64 X-rows = 4 m-frags of 16; A
// (fp8) in regs (64). Each wave owns a PRIVATE 16KB LDS region = 2 x 8KB
// B-tile buffers, staged by global_load_lds (linear dest + pre-swizzled src,
// XOR (row&7)<<4). NO barriers: per-wave counted s_waitcnt vmcnt(8) (= one
// 8-op stage in flight). stage(t+2) issues after tile t's MFMAs (its
// ds_reads are retired by then; sched_barrier(0) pins the order). Schedule:
//   S0 S1 | [W8 C0 S2] [W8 C1 S3] ... [W8 C14 -] [W0 C15]
// W8 at iter t guarantees S(t) landed (vmem completes in-order); S(t+1) may
// stay in flight; S(t+2) overwrites the buffer C(t) just finished reading.
__global__ __launch_bounds__(256, 2) void logits_kernel(
    const unsigned char* __restrict__ Xq,
    const unsigned char* __restrict__ Yq,
    float* __restrict__ row_sum)
{
  __shared__ char lds[4 * 16384];   // wave w owns [w*16384, +16KB): 2 bufs x 8KB
  const int tid  = threadIdx.x;
  const int lane = tid & 63;
  const int wave = tid >> 6;
  const int l15  = lane & 15;
  const int g    = lane >> 4;      // 0..3: k-group / C-row group

  // XCD-aware bijective map: xcd=bid&7 owns 16 panels x 4 splits
  const int bid  = blockIdx.x;
  const int xcd  = bid & 7;
  const int idx  = bid >> 3;                        // 0..63
  const int panel = (xcd >> 2) * 16 + (idx & 15);   // 0..31
  const int split = (xcd & 3) * 4 + (idx >> 4);     // 0..15

  const int rowbase = panel * 256 + wave * 64;
  const char* Xb = (const char*)Xq;
  const char* Yb = (const char*)Yq + (size_t)split * (512 * 256);
  char* myb = lds + wave * 16384;

  // A fragments (16x16x128 fp8): lane holds row (rowbase+16m+l15),
  // k-bytes [kb*128 + g*32, +32) -> i32x8 (32B, aligned).
  i32x8 a[4][2];
  #pragma unroll
  for (int m = 0; m < 4; ++m) {
    const char* rp = Xb + (size_t)(rowbase + m * 16 + l15) * 256 + g * 32;
    a[m][0] = *(const i32x8*)(rp);
    a[m][1] = *(const i32x8*)(rp + 128);
  }

  f32x2 sums2[4][2];
  #pragma unroll
  for (int m = 0; m < 4; ++m) {
    sums2[m][0] = (f32x2){0.f, 0.f};
    sums2[m][1] = (f32x2){0.f, 0.f};
  }

  // B read offsets within a tile: lane reads Y-row r = n*16+l15, bytes
  // kb*128 + g*32 (+16), stored XOR-swizzled within each 256B row.
  const int sr = (l15 & 7) << 4;
  const int gx = (g * 32) ^ sr;
  int bb[2][2];
  #pragma unroll
  for (int n = 0; n < 2; ++n) {
    bb[n][0] = (n * 16 + l15) * 256 + gx;
    bb[n][1] = bb[n][0] ^ 16;
  }

  // Stage one full 8KB tile into THIS wave's buffer: exactly 8 vmem ops.
  auto stage = [&](int t, int buf) {
    const char* Yt = Yb + (size_t)t * 8192;
    char* db = myb + buf * 8192;
    #pragma unroll
    for (int s = 0; s < 8; ++s) {
      const int L = s * 1024 + lane * 16;
      const int src = (L & ~255) | ((L & 255) ^ (((L >> 8) & 7) << 4));
      __builtin_amdgcn_global_load_lds(AS1(Yt + src), AS3(db + s * 1024), 16, 0, 0);
    }
  };

  // T15 double-acc: accA = cur of even tiles, accB = cur of odd tiles.
  // accB starts at -inf so tile 0's "prev" exp contributes exactly 0.
  f32x4 accA[4][2], accB[4][2];
  #pragma unroll
  for (int m = 0; m < 4; ++m)
    #pragma unroll
    for (int n = 0; n < 2; ++n) {
      accA[m][n] = (f32x4){0.f, 0.f, 0.f, 0.f};
      const float ni = -__builtin_inff();
      accB[m][n] = (f32x4){ni, ni, ni, ni};
    }

  stage(0, 0);
  stage(1, 1);
  #pragma unroll 1
  for (int p = 0; p < 8; ++p) {
    const int t = 2 * p;
    // even tile t: buffer 0
    asm volatile("s_waitcnt vmcnt(8)" ::: "memory");
    tile_step(myb, bb, a, accA, accB, sums2);
    __builtin_amdgcn_sched_barrier(0);
    if (t + 2 < 16) stage(t + 2, 0);
    // odd tile t+1: buffer 1
    if (p < 7) {
      asm volatile("s_waitcnt vmcnt(8)" ::: "memory");
    } else {
      asm volatile("s_waitcnt vmcnt(0)" ::: "memory");
    }
    tile_step(myb + 8192, bb, a, accB, accA, sums2);
    __builtin_amdgcn_sched_barrier(0);
    if (t + 3 < 16) stage(t + 3, 1);
  }
  // flush tile 15 (its results live in accB)
  #pragma unroll
  for (int m = 0; m < 4; ++m)
    expflush(accB[m], sums2[m]);

  // reduce across the 16 column-lanes; one atomic per row per split.
  // C/D mapping (16x16 family, R1-verified): col=l15, row = g*4 + reg.
  #pragma unroll
  for (int m = 0; m < 4; ++m)
    #pragma unroll
    for (int h = 0; h < 2; ++h)
      #pragma unroll
      for (int r2 = 0; r2 < 2; ++r2) {
        float s = (r2 == 0) ? sums2[m][h].x : sums2[m][h].y;
        s += __shfl_xor(s, 1);
        s += __shfl_xor(s, 2);
        s += __shfl_xor(s, 4);
        s += __shfl_xor(s, 8);
        if (l15 == 0)
          atomicAdd(row_sum + rowbase + m * 16 + g * 4 + h * 2 + r2, s);
      }
}

// ---------------- loss: single-kernel reduction ----------------
__global__ __launch_bounds__(1024) void loss_kernel(
    const float* __restrict__ row_sum, const float* __restrict__ diag,
    float* __restrict__ out)
{
  const int t = threadIdx.x;
  double acc = 0.0;
  #pragma unroll
  for (int h = 0; h < 2; ++h) {
    const int i = h * 4096 + t * 4;
    const float4 s = *(const float4*)(row_sum + i);
    const float4 d = *(const float4*)(diag + i);
    acc += (double)(kInvT + LOG2F(s.x) * kLn2 - d.x);
    acc += (double)(kInvT + LOG2F(s.y) * kLn2 - d.y);
    acc += (double)(kInvT + LOG2F(s.z) * kLn2 - d.z);
    acc += (double)(kInvT + LOG2F(s.w) * kLn2 - d.w);
  }
  #pragma unroll
  for (int m = 1; m < 64; m <<= 1) acc += __shfl_xor(acc, m);
  __shared__ double red[16];
  if ((t & 63) == 0) red[t >> 6] = acc;
  __syncthreads();
  if (t == 0) {
    double tot = 0.0;
    #pragma unroll
    for (int w = 0; w < 16; ++w) tot += red[w];
    out[0] = (float)(tot / (double)BROWS);
  }
}

extern "C" void kernel_launch(void* const* d_in, const int* in_sizes, int n_in,
                              void* d_out, int out_size, void* d_ws, size_t ws_size,
                              hipStream_t stream) {
  (void)in_sizes; (void)n_in; (void)out_size; (void)ws_size;
  const float* X = (const float*)d_in[0];
  const float* Y = (const float*)d_in[1];
  char* w = (char*)d_ws;
  unsigned int* Xq = (unsigned int*)(w);
  unsigned int* Yq = (unsigned int*)(w + (2u << 20));
  float* diag    = (float*)(w + (4u << 20));
  float* row_sum = (float*)(w + (4u << 20) + (32u << 10));

  nrm_kernel<<<BROWS / 4, 256, 0, stream>>>(X, Y, Xq, Yq, diag, row_sum);
  logits_kernel<<<512, 256, 0, stream>>>((const unsigned char*)Xq,
                                         (const unsigned char*)Yq, row_sum);
  loss_kernel<<<1, 1024, 0, stream>>>(row_sum, diag, (float*)d_out);
}

// Round 9
// 34.739 us; speedup vs baseline: 1.0533x; 1.0533x over previous
//
#include <hip/hip_runtime.h>
#include <hip/hip_bf16.h>

// InfoNCE-style loss: Xn=normalize(X), Yn=normalize(Y), logits=Xn@Yn^T/0.07,
// loss = mean_i(lse_i - logits[i,i]).
// Fixed-max trick: logits <= 1/T, so lse = 1/T + ln(sum_j exp(logit-1/T)).
// fp8 e4m3 inputs, MX-scaled mfma_scale_f32_16x16x128_f8f6f4, scale=1.0.
// R9: shared staging (67MB total, not R8's 268MB) + m201-style counted
// vmcnt(4)+s_barrier per tile (loads stay in flight ACROSS barriers; no
// drain-to-0 in the loop) + full 4-bit LDS swizzle (2-way = conflict-free,
// vs R7/R8's 3-bit -> 4-way).
//
// ws layout:
//   [0,2MB)        Xq fp8 [8192][256]
//   [2MB,4MB)      Yq fp8 [8192][256]
//   [4MB,+32KB)    diag f32[8192]
//   [4MB+32K,+32K) row_sum f32[8192]  (zeroed by nrm_kernel each call)

typedef __attribute__((ext_vector_type(2)))  float f32x2;
typedef __attribute__((ext_vector_type(4)))  float f32x4;
typedef __attribute__((ext_vector_type(4)))  int   i32x4;
typedef __attribute__((ext_vector_type(8)))  int   i32x8;

#define AS1(p) ((const __attribute__((address_space(1))) void*)(uintptr_t)(p))
#define AS3(p) ((__attribute__((address_space(3))) void*)(uintptr_t)(p))

constexpr int   BROWS = 8192;
constexpr int   DDIM  = 256;
constexpr float kInvT = 14.285714285714286f;   // 1/0.07
constexpr float kC1   = 20.609929155556622f;   // log2(e)/0.07
constexpr float kLn2  = 0.6931471805599453f;
constexpr int   kSC   = 0x7F7F7F7F;            // e8m0 scale bytes = 2^0 = 1.0

#if __has_builtin(__builtin_amdgcn_exp2f)
#define EXP2F(x) __builtin_amdgcn_exp2f(x)
#else
#define EXP2F(x) exp2f(x)
#endif
#if __has_builtin(__builtin_amdgcn_logf)
#define LOG2F(x) __builtin_amdgcn_logf(x)
#else
#define LOG2F(x) log2f(x)
#endif

// ---- f32 -> fp8 e4m3fn (RNE). Inputs here are |v| <= 1, finite. ----
static __device__ __forceinline__ unsigned f2fp8(float f) {
  unsigned u = __builtin_bit_cast(unsigned, f);
  unsigned s = (u >> 24) & 0x80u;
  float af = __builtin_fabsf(f);
  if (af < 0.015625f) {                    // below min normal 2^-6: denorm steps 2^-9
    int q = (int)__builtin_rintf(af * 512.0f);   // 0..8 (8 rolls into min normal)
    return s | (unsigned)q;
  }
  unsigned au = u & 0x7FFFFFFFu;
  au += 0x7FFFFu + ((au >> 20) & 1u);      // RNE on 3-bit mantissa
  unsigned e8 = ((au >> 23) - 127u + 7u) & 0xFu;
  unsigned m  = (au >> 20) & 7u;
  return s | (e8 << 3) | m;
}

// ---------------- normalize rows -> fp8, exact fp32 diagonal, zero row_sum --
__global__ __launch_bounds__(256) void nrm_kernel(
    const float* __restrict__ X, const float* __restrict__ Y,
    unsigned int* __restrict__ Xq, unsigned int* __restrict__ Yq,
    float* __restrict__ diag, float* __restrict__ row_sum)
{
  const int wave = threadIdx.x >> 6;
  const int lane = threadIdx.x & 63;
  const int row  = blockIdx.x * 4 + wave;
  const float4 x = *(const float4*)(X + (size_t)row * DDIM + lane * 4);
  const float4 y = *(const float4*)(Y + (size_t)row * DDIM + lane * 4);
  float ssx = x.x*x.x + x.y*x.y + x.z*x.z + x.w*x.w;
  float ssy = y.x*y.x + y.y*y.y + y.z*y.z + y.w*y.w;
  float dot = x.x*y.x + x.y*y.y + x.z*y.z + x.w*y.w;
  #pragma unroll
  for (int m = 1; m < 64; m <<= 1) {
    ssx += __shfl_xor(ssx, m);
    ssy += __shfl_xor(ssy, m);
    dot += __shfl_xor(dot, m);
  }
  const float invx = 1.0f / fmaxf(sqrtf(ssx), 1e-8f);
  const float invy = 1.0f / fmaxf(sqrtf(ssy), 1e-8f);
#if __has_builtin(__builtin_amdgcn_cvt_pk_fp8_f32)
  int xq = __builtin_amdgcn_cvt_pk_fp8_f32(x.x * invx, x.y * invx, 0, false);
  xq     = __builtin_amdgcn_cvt_pk_fp8_f32(x.z * invx, x.w * invx, xq, true);
  int yq = __builtin_amdgcn_cvt_pk_fp8_f32(y.x * invy, y.y * invy, 0, false);
  yq     = __builtin_amdgcn_cvt_pk_fp8_f32(y.z * invy, y.w * invy, yq, true);
#else
  int xq = (int)(f2fp8(x.x*invx) | (f2fp8(x.y*invx) << 8) |
                 (f2fp8(x.z*invx) << 16) | (f2fp8(x.w*invx) << 24));
  int yq = (int)(f2fp8(y.x*invy) | (f2fp8(y.y*invy) << 8) |
                 (f2fp8(y.z*invy) << 16) | (f2fp8(y.w*invy) << 24));
#endif
  Xq[row * 64 + lane] = (unsigned)xq;
  Yq[row * 64 + lane] = (unsigned)yq;
  if (lane == 0) {
    diag[row] = dot * invx * invy * kInvT;
    row_sum[row] = 0.0f;
  }
}

// -------- exp-flush of one m-slice of the PREVIOUS tile's accumulators ------
static __device__ __forceinline__ void expflush(f32x4 (&pm)[2], f32x2 (&sm)[2]) {
  #pragma unroll
  for (int n = 0; n < 2; ++n) {
    f32x2 v0 = { pm[n][0], pm[n][1] };
    f32x2 v1 = { pm[n][2], pm[n][3] };
    v0 = v0 * kC1 + (f32x2){-kC1, -kC1};   // v_pk_fma_f32
    v1 = v1 * kC1 + (f32x2){-kC1, -kC1};
    sm[0] += (f32x2){ EXP2F(v0.x), EXP2F(v0.y) };
    sm[1] += (f32x2){ EXP2F(v1.x), EXP2F(v1.y) };
  }
}

// -------- one B-tile (32 Y-rows x 256B fp8): 16 MX-MFMAs + T15 exp overlap --
// Reads use XOR-composed addresses: addr = bb[n] ^ {0,16,128,144} (4-bit
// slot swizzle puts kb in the XOR key, so kb=1 is ^128 not +128).
static __device__ __forceinline__ void tile_step(
    const char* __restrict__ tb, const int (&bb)[2], const i32x8 (&a)[4][2],
    f32x4 (&cur)[4][2], f32x4 (&prev)[4][2], f32x2 (&sums2)[4][2])
{
  i32x8 b[2];
  __builtin_amdgcn_s_setprio(1);
  #pragma unroll
  for (int n = 0; n < 2; ++n) {
    const i32x4 lo = *(const i32x4*)(tb + (bb[n]));
    const i32x4 hi = *(const i32x4*)(tb + (bb[n] ^ 16));
    b[n] = __builtin_shufflevector(lo, hi, 0, 1, 2, 3, 4, 5, 6, 7);
  }
  #pragma unroll
  for (int m = 0; m < 4; ++m) {
    cur[m][0] = __builtin_amdgcn_mfma_scale_f32_16x16x128_f8f6f4(
        a[m][0], b[0], (f32x4){0.f, 0.f, 0.f, 0.f}, 0, 0, 0, kSC, 0, kSC);
    cur[m][1] = __builtin_amdgcn_mfma_scale_f32_16x16x128_f8f6f4(
        a[m][0], b[1], (f32x4){0.f, 0.f, 0.f, 0.f}, 0, 0, 0, kSC, 0, kSC);
  }
  __builtin_amdgcn_s_setprio(0);
  expflush(prev[0], sums2[0]);
  expflush(prev[1], sums2[1]);
  __builtin_amdgcn_s_setprio(1);
  #pragma unroll
  for (int n = 0; n < 2; ++n) {
    const i32x4 lo = *(const i32x4*)(tb + (bb[n] ^ 128));
    const i32x4 hi = *(const i32x4*)(tb + (bb[n] ^ 144));
    b[n] = __builtin_shufflevector(lo, hi, 0, 1, 2, 3, 4, 5, 6, 7);
  }
  #pragma unroll
  for (int m = 0; m < 4; ++m) {
    cur[m][0] = __builtin_amdgcn_mfma_scale_f32_16x16x128_f8f6f4(
        a[m][1], b[0], cur[m][0], 0, 0, 0, kSC, 0, kSC);
    cur[m][1] = __builtin_amdgcn_mfma_scale_f32_16x16x128_f8f6f4(
        a[m][1], b[1], cur[m][1], 0, 0, 0, kSC, 0, kSC);
  }
  __builtin_amdgcn_s_setprio(0);
  expflush(prev[2], sums2[2]);
  expflush(prev[3], sums2[3]);
}

// ---------------- main: exp-sum of logits over all columns ----------------
// 512 blocks x 256 thr (4 waves). Wave owns 64 X-rows = 4 m-frags of 16; A
// (fp8) in regs (64). Shared B tiles: 32 Y-rows x 256B (8KB), 4-deep ring
// (32KB LDS), all 4 waves co-stage (2 x 1KB global_load_lds each).
// LDS swizzle: byte (r,c) stored at r*256 + (((c>>4) ^ (r&15))<<4 | (c&15))
// -> every ds_read_b128 is 2 lanes/slot = conflict-free; staging stays
// width-16 with pre-swizzled source.
// Schedule per tile t (m201 counted-vmcnt pattern, never drain in-loop):
//   s_waitcnt vmcnt(4)   ; my 2 ops for tile t retired (t+1..t+3 in flight)
//   s_barrier            ; all waves' portions of t landed; t-1 fully read
//   stage(t+3)           ; overwrites buf[(t-1)&3], safe after barrier
//   tile_step(buf[t&3])
// Epilogue waits: t=14 -> vmcnt(2), t=15 -> vmcnt(0).
__global__ __launch_bounds__(256, 2) void logits_kernel(
    const unsigned char* __restrict__ Xq,
    const unsigned char* __restrict__ Yq,
    float* __restrict__ row_sum)
{
  __shared__ char lds[4 * 8192];
  const int tid  = threadIdx.x;
  const int lane = tid & 63;
  const int wave = tid >> 6;
  const int l15  = lane & 15;
  const int g    = lane >> 4;      // 0..3: k-group / C-row group

  // XCD-aware bijective map: xcd=bid&7 owns 16 panels x 4 splits
  const int bid  = blockIdx.x;
  const int xcd  = bid & 7;
  const int idx  = bid >> 3;                        // 0..63
  const int panel = (xcd >> 2) * 16 + (idx & 15);   // 0..31
  const int split = (xcd & 3) * 4 + (idx >> 4);     // 0..15

  const int rowbase = panel * 256 + wave * 64;
  const char* Xb = (const char*)Xq;
  const char* Yb = (const char*)Yq + (size_t)split * (512 * 256);

  // A fragments (16x16x128 fp8): lane holds row (rowbase+16m+l15),
  // k-bytes [kb*128 + g*32, +32) -> i32x8 (32B, aligned).
  i32x8 a[4][2];
  #pragma unroll
  for (int m = 0; m < 4; ++m) {
    const char* rp = Xb + (size_t)(rowbase + m * 16 + l15) * 256 + g * 32;
    a[m][0] = *(const i32x8*)(rp);
    a[m][1] = *(const i32x8*)(rp + 128);
  }

  f32x2 sums2[4][2];
  #pragma unroll
  for (int m = 0; m < 4; ++m) {
    sums2[m][0] = (f32x2){0.f, 0.f};
    sums2[m][1] = (f32x2){0.f, 0.f};
  }

  // B read bases: row r = n*16+l15, slot s16 = kb*8 + 2g + h, swizzled
  // slot' = s16 ^ l15  ->  base (kb=0,h=0): r*256 + ((2g ^ l15)<<4);
  // other three reads are base ^ 16 (h), ^128 (kb), ^144 (both).
  int bb[2];
  #pragma unroll
  for (int n = 0; n < 2; ++n)
    bb[n] = (n * 16 + l15) * 256 + (((2 * g) ^ l15) << 4);

  // Co-staged: wave stages 2KB of the 8KB tile (2 x width-16 ops).
  auto stage = [&](int t, int buf) {
    const char* Yt = Yb + (size_t)t * 8192;
    char* db = lds + buf * 8192;
    #pragma unroll
    for (int s = 0; s < 2; ++s) {
      const int portion = (s * 4 + wave) * 1024;
      const int L = portion + lane * 16;
      const int src = (L & ~255) | ((L & 255) ^ (((L >> 8) & 15) << 4));
      __builtin_amdgcn_global_load_lds(AS1(Yt + src), AS3(db + portion), 16, 0, 0);
    }
  };

  // T15 double-acc: accA = cur of even tiles, accB = cur of odd tiles.
  // accB starts at -inf so tile 0's "prev" exp contributes exactly 0.
  f32x4 accA[4][2], accB[4][2];
  #pragma unroll
  for (int m = 0; m < 4; ++m)
    #pragma unroll
    for (int n = 0; n < 2; ++n) {
      accA[m][n] = (f32x4){0.f, 0.f, 0.f, 0.f};
      const float ni = -__builtin_inff();
      accB[m][n] = (f32x4){ni, ni, ni, ni};
    }

  stage(0, 0);
  stage(1, 1);
  stage(2, 2);
  #pragma unroll 1
  for (int p = 0; p < 8; ++p) {
    const int t = 2 * p;
    // even tile t
    if (p < 7) asm volatile("s_waitcnt vmcnt(4)" ::: "memory");
    else       asm volatile("s_waitcnt vmcnt(2)" ::: "memory");
    __builtin_amdgcn_s_barrier();
    if (t + 3 < 16) stage(t + 3, (t + 3) & 3);
    tile_step(lds + (t & 3) * 8192, bb, a, accA, accB, sums2);
    // odd tile t+1
    if (p < 7) asm volatile("s_waitcnt vmcnt(4)" ::: "memory");
    else       asm volatile("s_waitcnt vmcnt(0)" ::: "memory");
    __builtin_amdgcn_s_barrier();
    if (t + 4 < 16) stage(t + 4, (t + 4) & 3);
    tile_step(lds + ((t + 1) & 3) * 8192, bb, a, accB, accA, sums2);
  }
  // flush tile 15 (its results live in accB)
  #pragma unroll
  for (int m = 0; m < 4; ++m)
    expflush(accB[m], sums2[m]);

  // reduce across the 16 column-lanes; one atomic per row per split.
  // C/D mapping (16x16 family, R1-verified): col=l15, row = g*4 + reg.
  #pragma unroll
  for (int m = 0; m < 4; ++m)
    #pragma unroll
    for (int h = 0; h < 2; ++h)
      #pragma unroll
      for (int r2 = 0; r2 < 2; ++r2) {
        float s = (r2 == 0) ? sums2[m][h].x : sums2[m][h].y;
        s += __shfl_xor(s, 1);
        s += __shfl_xor(s, 2);
        s += __shfl_xor(s, 4);
        s += __shfl_xor(s, 8);
        if (l15 == 0)
          atomicAdd(row_sum + rowbase + m * 16 + g * 4 + h * 2 + r2, s);
      }
}

// ---------------- loss: single-kernel reduction ----------------
__global__ __launch_bounds__(1024) void loss_kernel(
    const float* __restrict__ row_sum, const float* __restrict__ diag,
    float* __restrict__ out)
{
  const int t = threadIdx.x;
  double acc = 0.0;
  #pragma unroll
  for (int h = 0; h < 2; ++h) {
    const int i = h * 4096 + t * 4;
    const float4 s = *(const float4*)(row_sum + i);
    const float4 d = *(const float4*)(diag + i);
    acc += (double)(kInvT + LOG2F(s.x) * kLn2 - d.x);
    acc += (double)(kInvT + LOG2F(s.y) * kLn2 - d.y);
    acc += (double)(kInvT + LOG2F(s.z) * kLn2 - d.z);
    acc += (double)(kInvT + LOG2F(s.w) * kLn2 - d.w);
  }
  #pragma unroll
  for (int m = 1; m < 64; m <<= 1) acc += __shfl_xor(acc, m);
  __shared__ double red[16];
  if ((t & 63) == 0) red[t >> 6] = acc;
  __syncthreads();
  if (t == 0) {
    double tot = 0.0;
    #pragma unroll
    for (int w = 0; w < 16; ++w) tot += red[w];
    out[0] = (float)(tot / (double)BROWS);
  }
}

extern "C" void kernel_launch(void* const* d_in, const int* in_sizes, int n_in,
                              void* d_out, int out_size, void* d_ws, size_t ws_size,
                              hipStream_t stream) {
  (void)in_sizes; (void)n_in; (void)out_size; (void)ws_size;
  const float* X = (const float*)d_in[0];
  const float* Y = (const float*)d_in[1];
  char* w = (char*)d_ws;
  unsigned int* Xq = (unsigned int*)(w);
  unsigned int* Yq = (unsigned int*)(w + (2u << 20));
  float* diag    = (float*)(w + (4u << 20));
  float* row_sum = (float*)(w + (4u << 20) + (32u << 10));

  nrm_kernel<<<BROWS / 4, 256, 0, stream>>>(X, Y, Xq, Yq, diag, row_sum);
  logits_kernel<<<512, 256, 0, stream>>>((const unsigned char*)Xq,
                                         (const unsigned char*)Yq, row_sum);
  loss_kernel<<<1, 1024, 0, stream>>>(row_sum, diag, (float*)d_out);
}